// Round 4
// baseline (927.731 us; speedup 1.0000x reference)
//
#include <hip/hip_runtime.h>

#define D_IN 40960
#define NB 2048
#define BASEN 288
#define CAPL 95        // max indices kept per (row,color); mean ~41, sigma ~6.4
#define LSTRIDE 96     // ints per list: [count, idx0..idx94]
#define KP 736         // 160 (a0 padded) + 576 (base)

typedef __attribute__((ext_vector_type(4))) float f32x4;
typedef __attribute__((ext_vector_type(8))) short short8;

__device__ inline float bf2f(ushort u) {
    unsigned v = ((unsigned)u) << 16; float f; __builtin_memcpy(&f, &v, 4); return f;
}
__device__ inline ushort f2bf(float f) {
    unsigned x; __builtin_memcpy(&x, &f, 4);
    unsigned r = (x + 0x7FFFu + ((x >> 16) & 1u)) >> 16; return (ushort)r;
}

__device__ inline void llds16(const void* g, void* l) {
    __builtin_amdgcn_global_load_lds((const __attribute__((address_space(1))) unsigned*)g,
                                     (__attribute__((address_space(3))) unsigned*)l, 16, 0, 0);
}

// ---------------- kernel 1: find nonzero indices per (row, color); input f32 0/1 ----------------
__global__ __launch_bounds__(256) void scan_kernel(const float* __restrict__ white,
                                                   const float* __restrict__ black,
                                                   int* __restrict__ lists) {
    int b = blockIdx.x, c = blockIdx.y;
    const float* src = (c ? black : white) + (size_t)b * D_IN;
    __shared__ int cnt;
    __shared__ int idxs[CAPL];
    if (threadIdx.x == 0) cnt = 0;
    __syncthreads();
    const uint4* v = (const uint4*)src;   // 4 f32 per uint4
    for (int it = 0; it < D_IN / (256 * 4); ++it) {
        int vi = it * 256 + threadIdx.x;
        uint4 x = v[vi];
        unsigned wds[4] = {x.x, x.y, x.z, x.w};
#pragma unroll
        for (int q = 0; q < 4; ++q) {
            if (wds[q]) { int p = atomicAdd(&cnt, 1); if (p < CAPL) idxs[p] = vi * 4 + q; }
        }
    }
    __syncthreads();
    int n = min(cnt, CAPL);
    int* dst = lists + ((size_t)c * NB + b) * LSTRIDE;
    if (threadIdx.x == 0) dst[0] = n;
    for (int i = threadIdx.x; i < n; i += 256) dst[1 + i] = idxs[i];
}

// ---------------- kernel 2: transpose W f32 [288,40960] -> Wt bf16 [40960,288] ----------------
__global__ __launch_bounds__(256) void transpose_kernel(const float* __restrict__ src,
                                                        ushort* __restrict__ dst) {
    __shared__ float tile[32][65];
    int i = threadIdx.x;
    int d0 = blockIdx.x * 64, o0 = blockIdx.y * 32;
    int tr = i >> 4, tc4 = (i & 15) * 4;
#pragma unroll
    for (int rep = 0; rep < 2; ++rep) {
        int row = tr + rep * 16;
        float4 u = *(const float4*)&src[(size_t)(o0 + row) * D_IN + d0 + tc4];
        tile[row][tc4] = u.x; tile[row][tc4 + 1] = u.y; tile[row][tc4 + 2] = u.z; tile[row][tc4 + 3] = u.w;
    }
    __syncthreads();
    int dr = i >> 3, oc4 = (i & 7) * 4;
#pragma unroll
    for (int rep = 0; rep < 2; ++rep) {
        int d = dr + rep * 32;
        ushort4 u;
        u.x = f2bf(tile[oc4][d]); u.y = f2bf(tile[oc4 + 1][d]);
        u.z = f2bf(tile[oc4 + 2][d]); u.w = f2bf(tile[oc4 + 3][d]);
        *(ushort4*)&dst[(size_t)(d0 + d) * BASEN + o0 + oc4] = u;
    }
}

// ---------------- kernel 3: white gather -> accW (f32) ----------------
__global__ __launch_bounds__(288) void gatherW_kernel(const int* __restrict__ lists,
                                                      const ushort* __restrict__ Wt,
                                                      const float* __restrict__ b_w,
                                                      float* __restrict__ accW) {
    int b = blockIdx.x, t = threadIdx.x;
    __shared__ int idx[CAPL];
    __shared__ int ncnt;
    const int* lw = lists + (size_t)b * LSTRIDE;
    if (t == 0) ncnt = min(lw[0], CAPL);
    for (int i = t; i < CAPL; i += 288) idx[i] = lw[1 + i];
    __syncthreads();
    float acc = b_w[t];
    int n = ncnt;
#pragma unroll 4
    for (int i = 0; i < n; ++i) acc += bf2f(Wt[(size_t)idx[i] * BASEN + t]);
    accW[(size_t)b * BASEN + t] = acc;
}

// ---------------- kernel 4: black gather + pov mix + relu + a0, writes hidden (bf16) ----------------
// hidden row layout [736]: [0..143]=a0, [144..159]=0, [160..735]=base
__global__ __launch_bounds__(288) void gatherB_kernel(const int* __restrict__ lists,
                                                      const ushort* __restrict__ Wt,
                                                      const float* __restrict__ accW,
                                                      const float* __restrict__ pov,
                                                      const float* __restrict__ b_b,
                                                      const float* __restrict__ W_a0,
                                                      const float* __restrict__ b_a0,
                                                      ushort* __restrict__ hidden) {
    int b = blockIdx.x, t = threadIdx.x;
    __shared__ int idx[CAPL];
    __shared__ int ncnt;
    __shared__ float baseS[576];
    const int* lb = lists + ((size_t)NB + b) * LSTRIDE;
    if (t == 0) ncnt = min(lb[0], CAPL);
    for (int i = t; i < CAPL; i += 288) idx[i] = lb[1 + i];
    __syncthreads();
    float accB = b_b[t];
    int n = ncnt;
#pragma unroll 4
    for (int i = 0; i < n; ++i) accB += bf2f(Wt[(size_t)idx[i] * BASEN + t]);
    float aW = accW[(size_t)b * BASEN + t];
    float p = pov[b];
    float b0 = fmaxf(p * aW + (1.0f - p) * accB, 0.0f);   // base[t]
    float b1 = fmaxf(p * accB + (1.0f - p) * aW, 0.0f);   // base[288+t]
    baseS[t] = b0; baseS[288 + t] = b1;
    ushort* hrow = hidden + (size_t)b * KP;
    hrow[160 + t] = f2bf(b0);
    hrow[160 + 288 + t] = f2bf(b1);
    if (t < 16) hrow[144 + t] = 0;
    __syncthreads();
    // a0[o] = relu(base . W_a0[o,:] + b_a0[o]); 2 threads per o, 288 k each
    int o = t >> 1, half = t & 1;
    const float* wrow = W_a0 + (size_t)o * 576 + half * 288;
    const float* bp = &baseS[half * 288];
    float s = 0.f;
#pragma unroll
    for (int j = 0; j < 288; j += 4) {
        float4 q = *(const float4*)(wrow + j);
        s += bp[j + 0] * q.x + bp[j + 1] * q.y + bp[j + 2] * q.z + bp[j + 3] * q.w;
    }
    s += __shfl_xor(s, 1);
    if (half == 0) hrow[o] = f2bf(fmaxf(s + b_a0[o], 0.f));
}

// ---------------- kernel 5: build Wcat bf16 [4096,736] = [W_a1 | 0pad | W_as]; biasA ----------------
__global__ __launch_bounds__(256) void wcat_kernel(const float* __restrict__ W_a1,
                                                   const float* __restrict__ W_as,
                                                   const float* __restrict__ b_a1,
                                                   const float* __restrict__ b_as,
                                                   ushort* __restrict__ Wcat,
                                                   float* __restrict__ biasA) {
    int m = blockIdx.x, t = threadIdx.x;
    ushort* dst = Wcat + (size_t)m * KP;
    if (t < 144) dst[t] = f2bf(W_a1[(size_t)m * 144 + t]);
    if (t >= 144 && t < 160) dst[t] = 0;
    for (int j = t; j < 576; j += 256) dst[160 + j] = f2bf(W_as[(size_t)m * 576 + j]);
    if (t == 200) biasA[m] = b_a1[m] + b_as[m];
}

// ---------------- kernel 6: value head (f32 weights, base from hidden bf16), f32 out ----------------
__global__ __launch_bounds__(64) void val_kernel(const ushort* __restrict__ hidden,
                                                 const float* __restrict__ W_v0, const float* __restrict__ b_v0,
                                                 const float* __restrict__ W_v1, const float* __restrict__ b_v1,
                                                 const float* __restrict__ W_v2, const float* __restrict__ b_v2,
                                                 const float* __restrict__ W_vs, const float* __restrict__ b_vs,
                                                 float* __restrict__ outv) {
    int b = blockIdx.x, t = threadIdx.x;
    __shared__ float bl[576];
    __shared__ float v0s[32];
    __shared__ float skipS;
    const ushort* hrow = hidden + (size_t)b * KP + 160;
    for (int i = t; i < 576; i += 64) bl[i] = bf2f(hrow[i]);
    __syncthreads();
    if (t < 32) {
        float s = b_v0[t];
        const float* w = W_v0 + (size_t)t * 576;
        for (int j = 0; j < 576; ++j) s += bl[j] * w[j];
        v0s[t] = fmaxf(s, 0.f);
    } else {
        int u = t - 32;
        float s = 0.f;
        for (int j = u; j < 576; j += 32) s += bl[j] * W_vs[j];
        s += __shfl_xor(s, 1); s += __shfl_xor(s, 2); s += __shfl_xor(s, 4);
        s += __shfl_xor(s, 8); s += __shfl_xor(s, 16);
        if (u == 0) skipS = s;
    }
    __syncthreads();
    if (t < 32) {
        float s = b_v1[t];
        const float* w = W_v1 + (size_t)t * 32;
        for (int j = 0; j < 32; ++j) s += v0s[j] * w[j];
        float v1t = fmaxf(s, 0.f);
        float part = v1t * W_v2[t];
        part += __shfl_xor(part, 1); part += __shfl_xor(part, 2); part += __shfl_xor(part, 4);
        part += __shfl_xor(part, 8); part += __shfl_xor(part, 16);
        if (t == 0) outv[b] = part + b_v2[0] + skipS + b_vs[0];
    }
}

// ---------------- kernel 7: act GEMM (bf16 MFMA 16x16x32, 128x128 tiles), f32 out ----------------
__global__ __launch_bounds__(256) void gemm_act(const ushort* __restrict__ A,    // hidden [2048,736]
                                                const ushort* __restrict__ Bm,   // Wcat  [4096,736]
                                                const float* __restrict__ biasA, // [4096]
                                                float* __restrict__ outa) {      // [2048,4096] f32
    __shared__ ushort As[128 * 32];
    __shared__ ushort Bs[128 * 32];
    int tid = threadIdx.x;
    int lane = tid & 63, wv = tid >> 6;
    int bm = blockIdx.x, bn = blockIdx.y;
    int wm = wv & 1, wn = wv >> 1;
    f32x4 acc[4][4];
#pragma unroll
    for (int mt = 0; mt < 4; ++mt)
#pragma unroll
        for (int nt = 0; nt < 4; ++nt) { f32x4 z = {0.f, 0.f, 0.f, 0.f}; acc[mt][nt] = z; }

    int r = tid >> 2, c8 = (tid & 3) * 8;
    const ushort* Ag = A  + (size_t)(bm * 128 + r) * KP + c8;
    const ushort* Bg = Bm + (size_t)(bn * 128 + r) * KP + c8;
    ushort* AsW = As + wv * 512;
    ushort* BsW = Bs + wv * 512;

    int kg = (lane >> 4) * 8;
    int rA = wm * 64 + (lane & 15);
    int rB = wn * 64 + (lane & 15);

    for (int kk = 0; kk < KP; kk += 32) {
        llds16(Ag + kk, AsW);
        llds16(Ag + (size_t)64 * KP + kk, AsW + 2048);
        llds16(Bg + kk, BsW);
        llds16(Bg + (size_t)64 * KP + kk, BsW + 2048);
        __syncthreads();
        short8 af[4], bf[4];
#pragma unroll
        for (int mt = 0; mt < 4; ++mt) af[mt] = *(const short8*)&As[(rA + mt * 16) * 32 + kg];
#pragma unroll
        for (int nt = 0; nt < 4; ++nt) bf[nt] = *(const short8*)&Bs[(rB + nt * 16) * 32 + kg];
#pragma unroll
        for (int mt = 0; mt < 4; ++mt)
#pragma unroll
            for (int nt = 0; nt < 4; ++nt)
                acc[mt][nt] = __builtin_amdgcn_mfma_f32_16x16x32_bf16(af[mt], bf[nt], acc[mt][nt], 0, 0, 0);
        __syncthreads();
    }

    int colb = bn * 128 + wn * 64 + (lane & 15);
    int rowb = bm * 128 + wm * 64 + ((lane >> 4) << 2);
#pragma unroll
    for (int nt = 0; nt < 4; ++nt) {
        float bia = biasA[colb + nt * 16];
#pragma unroll
        for (int mt = 0; mt < 4; ++mt) {
#pragma unroll
            for (int q = 0; q < 4; ++q) {
                int rr = rowb + mt * 16 + q;
                outa[(size_t)rr * 4096 + colb + nt * 16] = acc[mt][nt][q] + bia;
            }
        }
    }
}

extern "C" void kernel_launch(void* const* d_in, const int* in_sizes, int n_in,
                              void* d_out, int out_size, void* d_ws, size_t ws_size,
                              hipStream_t stream) {
    const float* pov   = (const float*)d_in[0];
    const float* white = (const float*)d_in[1];
    const float* black = (const float*)d_in[2];
    const float* W_w   = (const float*)d_in[3];
    const float* b_w   = (const float*)d_in[4];
    const float* W_b   = (const float*)d_in[5];
    const float* b_b   = (const float*)d_in[6];
    const float* W_v0  = (const float*)d_in[7];
    const float* b_v0  = (const float*)d_in[8];
    const float* W_v1  = (const float*)d_in[9];
    const float* b_v1  = (const float*)d_in[10];
    const float* W_v2  = (const float*)d_in[11];
    const float* b_v2  = (const float*)d_in[12];
    const float* W_a0  = (const float*)d_in[13];
    const float* b_a0  = (const float*)d_in[14];
    const float* W_a1  = (const float*)d_in[15];
    const float* b_a1  = (const float*)d_in[16];
    const float* W_vs  = (const float*)d_in[17];
    const float* b_vs  = (const float*)d_in[18];
    const float* W_as  = (const float*)d_in[19];
    const float* b_as  = (const float*)d_in[20];

    char* ws = (char*)d_ws;
    // ws layout — total 30,539,776 B (< 32 MiB), all offsets 16B-aligned.
    // Region [0, 23.6MB): Wt (bf16) during gather phase; REUSED afterwards for
    // Wcat (6,029,312 B) + biasA (16,384 B) — safe because same-stream ordering
    // puts wcat_kernel strictly after gatherB_kernel.
    ushort* Wtbuf = (ushort*)(ws + 0);          // 40960*288*2 = 23,592,960
    ushort* Wcat  = (ushort*)(ws + 0);          // 4096*736*2  = 6,029,312 (alias, later)
    float*  biasA = (float*)(ws + 6029312);     // 4096*4      = 16,384    (alias, later)
    int*    lists = (int*)  (ws + 23592960);    // 2*2048*96*4 = 1,572,864 -> 25,165,824
    float*  accW  = (float*)(ws + 25165824);    // 2048*288*4  = 2,359,296 -> 27,525,120
    ushort* hidden= (ushort*)(ws + 27525120);   // 2048*736*2  = 3,014,656 -> 30,539,776

    float* outp = (float*)d_out;

    scan_kernel<<<dim3(NB, 2), 256, 0, stream>>>(white, black, lists);
    transpose_kernel<<<dim3(D_IN / 64, BASEN / 32), 256, 0, stream>>>(W_w, Wtbuf);
    gatherW_kernel<<<NB, 288, 0, stream>>>(lists, Wtbuf, b_w, accW);
    transpose_kernel<<<dim3(D_IN / 64, BASEN / 32), 256, 0, stream>>>(W_b, Wtbuf);
    gatherB_kernel<<<NB, 288, 0, stream>>>(lists, Wtbuf, accW, pov, b_b, W_a0, b_a0, hidden);
    wcat_kernel<<<4096, 256, 0, stream>>>(W_a1, W_as, b_a1, b_as, Wcat, biasA);
    val_kernel<<<NB, 64, 0, stream>>>(hidden, W_v0, b_v0, W_v1, b_v1, W_v2, b_v2, W_vs, b_vs, outp);
    gemm_act<<<dim3(2048 / 128, 4096 / 128), 256, 0, stream>>>(hidden, Wcat, biasA, outp + 2048);
}

// Round 5
// 871.803 us; speedup vs baseline: 1.0642x; 1.0642x over previous
//
#include <hip/hip_runtime.h>

#define D_IN 40960
#define NB 2048
#define BASEN 288
#define CAPL 95        // max indices kept per (row,color); mean ~41, sigma ~6.4
#define KP 736         // 160 (a0 padded) + 576 (base)

typedef __attribute__((ext_vector_type(4))) float f32x4;
typedef __attribute__((ext_vector_type(8))) short short8;

__device__ inline float bf2f(ushort u) {
    unsigned v = ((unsigned)u) << 16; float f; __builtin_memcpy(&f, &v, 4); return f;
}
__device__ inline ushort f2bf(float f) {
    unsigned x; __builtin_memcpy(&x, &f, 4);
    unsigned r = (x + 0x7FFFu + ((x >> 16) & 1u)) >> 16; return (ushort)r;
}

__device__ inline void llds16(const void* g, void* l) {
    __builtin_amdgcn_global_load_lds((const __attribute__((address_space(1))) unsigned*)g,
                                     (__attribute__((address_space(3))) unsigned*)l, 16, 0, 0);
}

// ---------------- kernel 1: transpose W_w/W_b f32 [288,40960] -> Wt bf16 [40960,288] ----------------
__global__ __launch_bounds__(256) void transpose_kernel(const float* __restrict__ Ww,
                                                        const float* __restrict__ Wb,
                                                        ushort* __restrict__ Wtw,
                                                        ushort* __restrict__ Wtb) {
    const float* src = blockIdx.z ? Wb : Ww;
    ushort* dst = blockIdx.z ? Wtb : Wtw;
    __shared__ float tile[32][65];
    int i = threadIdx.x;
    int d0 = blockIdx.x * 64, o0 = blockIdx.y * 32;
    int tr = i >> 4, tc4 = (i & 15) * 4;
#pragma unroll
    for (int rep = 0; rep < 2; ++rep) {
        int row = tr + rep * 16;
        float4 u = *(const float4*)&src[(size_t)(o0 + row) * D_IN + d0 + tc4];
        tile[row][tc4] = u.x; tile[row][tc4 + 1] = u.y; tile[row][tc4 + 2] = u.z; tile[row][tc4 + 3] = u.w;
    }
    __syncthreads();
    int dr = i >> 3, oc4 = (i & 7) * 4;
#pragma unroll
    for (int rep = 0; rep < 2; ++rep) {
        int d = dr + rep * 32;
        ushort4 u;
        u.x = f2bf(tile[oc4][d]); u.y = f2bf(tile[oc4 + 1][d]);
        u.z = f2bf(tile[oc4 + 2][d]); u.w = f2bf(tile[oc4 + 3][d]);
        *(ushort4*)&dst[(size_t)(d0 + d) * BASEN + o0 + oc4] = u;
    }
}

// ---------------- kernel 2: prep — Wcat bf16 [4096,736], biasA, Wa0h bf16, Wv0h bf16 ----------------
__global__ __launch_bounds__(256) void prep_kernel(const float* __restrict__ W_a1,
                                                   const float* __restrict__ W_as,
                                                   const float* __restrict__ b_a1,
                                                   const float* __restrict__ b_as,
                                                   const float* __restrict__ W_a0,
                                                   const float* __restrict__ W_v0,
                                                   ushort* __restrict__ Wcat,
                                                   float* __restrict__ biasA,
                                                   ushort* __restrict__ Wa0h,
                                                   ushort* __restrict__ Wv0h) {
    int m = blockIdx.x, t = threadIdx.x;
    if (m < 4096) {
        ushort* dst = Wcat + (size_t)m * KP;
        if (t < 144) dst[t] = f2bf(W_a1[(size_t)m * 144 + t]);
        if (t >= 144 && t < 160) dst[t] = 0;
        for (int j = t; j < 576; j += 256) dst[160 + j] = f2bf(W_as[(size_t)m * 576 + j]);
        if (t == 200) biasA[m] = b_a1[m] + b_as[m];
    } else if (m < 4096 + 144) {
        int r = m - 4096;
        for (int j = t; j < 576; j += 256) Wa0h[(size_t)r * 576 + j] = f2bf(W_a0[(size_t)r * 576 + j]);
    } else {
        int r = m - (4096 + 144);      // 0..31
        for (int j = t; j < 576; j += 256) Wv0h[(size_t)r * 576 + j] = f2bf(W_v0[(size_t)r * 576 + j]);
    }
}

// ---------------- kernel 3: fused per-row: scan + gather + mix + a0 + value head ----------------
// hidden row layout [736]: [0..143]=a0, [144..159]=0, [160..735]=base
__global__ __launch_bounds__(576) void row_kernel(const float* __restrict__ white,
                                                  const float* __restrict__ black,
                                                  const ushort* __restrict__ Wtw,
                                                  const ushort* __restrict__ Wtb,
                                                  const float* __restrict__ pov,
                                                  const float* __restrict__ b_w,
                                                  const float* __restrict__ b_b,
                                                  const ushort* __restrict__ Wa0h,
                                                  const float* __restrict__ b_a0,
                                                  const ushort* __restrict__ Wv0h,
                                                  const float* __restrict__ b_v0,
                                                  const float* __restrict__ W_v1,
                                                  const float* __restrict__ b_v1,
                                                  const float* __restrict__ W_v2,
                                                  const float* __restrict__ b_v2,
                                                  const float* __restrict__ W_vs,
                                                  const float* __restrict__ b_vs,
                                                  ushort* __restrict__ hidden,
                                                  float* __restrict__ outv) {
    int b = blockIdx.x, t = threadIdx.x;
    __shared__ int cntW, cntB;
    __shared__ int idxW[CAPL], idxB[CAPL];
    __shared__ float accS[576];
    __shared__ float baseS[576];
    __shared__ float v0s[32];
    __shared__ float skipS;
    if (t == 0) cntW = 0;
    if (t == 1) cntB = 0;
    __syncthreads();

    // --- phase A: scan both occupancy rows (671 MB total across grid — the HBM floor) ---
    const uint4* vw = (const uint4*)(white + (size_t)b * D_IN);
    const uint4* vb = (const uint4*)(black + (size_t)b * D_IN);
    for (int i = t; i < D_IN / 4; i += 576) {
        uint4 x = vw[i];
        if (x.x) { int p = atomicAdd(&cntW, 1); if (p < CAPL) idxW[p] = i * 4; }
        if (x.y) { int p = atomicAdd(&cntW, 1); if (p < CAPL) idxW[p] = i * 4 + 1; }
        if (x.z) { int p = atomicAdd(&cntW, 1); if (p < CAPL) idxW[p] = i * 4 + 2; }
        if (x.w) { int p = atomicAdd(&cntW, 1); if (p < CAPL) idxW[p] = i * 4 + 3; }
        uint4 y = vb[i];
        if (y.x) { int p = atomicAdd(&cntB, 1); if (p < CAPL) idxB[p] = i * 4; }
        if (y.y) { int p = atomicAdd(&cntB, 1); if (p < CAPL) idxB[p] = i * 4 + 1; }
        if (y.z) { int p = atomicAdd(&cntB, 1); if (p < CAPL) idxB[p] = i * 4 + 2; }
        if (y.w) { int p = atomicAdd(&cntB, 1); if (p < CAPL) idxB[p] = i * 4 + 3; }
    }
    __syncthreads();

    // --- phase B: gather-sum (threads 0..287 white, 288..575 black) ---
    {
        int col = (t < 288) ? t : t - 288;
        const ushort* Wt = (t < 288) ? Wtw : Wtb;
        const int* il = (t < 288) ? idxW : idxB;
        int n = min((t < 288) ? cntW : cntB, CAPL);
        float acc = (t < 288) ? b_w[col] : b_b[col];
#pragma unroll 4
        for (int i = 0; i < n; ++i) acc += bf2f(Wt[(size_t)il[i] * BASEN + col]);
        accS[t] = acc;
    }
    __syncthreads();

    // --- phase C: pov mix + relu -> baseS, write hidden base ---
    float p = pov[b];
    ushort* hrow = hidden + (size_t)b * KP;
    if (t < 288) {
        float aW = accS[t], aB = accS[288 + t];
        float b0 = fmaxf(p * aW + (1.0f - p) * aB, 0.0f);
        float b1 = fmaxf(p * aB + (1.0f - p) * aW, 0.0f);
        baseS[t] = b0; baseS[288 + t] = b1;
        hrow[160 + t] = f2bf(b0);
        hrow[160 + 288 + t] = f2bf(b1);
        if (t < 16) hrow[144 + t] = 0;
    }
    __syncthreads();

    // --- phase D: a0 = relu(W_a0 @ base + b_a0): 144 outputs x 4 threads x 144 k ---
    {
        int o = t >> 2, q4 = t & 3;
        const ushort* wr = Wa0h + (size_t)o * 576 + q4 * 144;
        const float* bp = &baseS[q4 * 144];
        float s = 0.f;
#pragma unroll
        for (int j = 0; j < 144; j += 8) {
            uint4 q = *(const uint4*)(wr + j);
            s += bp[j + 0] * bf2f((ushort)(q.x & 0xFFFF)) + bp[j + 1] * bf2f((ushort)(q.x >> 16))
               + bp[j + 2] * bf2f((ushort)(q.y & 0xFFFF)) + bp[j + 3] * bf2f((ushort)(q.y >> 16))
               + bp[j + 4] * bf2f((ushort)(q.z & 0xFFFF)) + bp[j + 5] * bf2f((ushort)(q.z >> 16))
               + bp[j + 6] * bf2f((ushort)(q.w & 0xFFFF)) + bp[j + 7] * bf2f((ushort)(q.w >> 16));
        }
        s += __shfl_xor(s, 1);
        s += __shfl_xor(s, 2);
        if (q4 == 0) hrow[o] = f2bf(fmaxf(s + b_a0[o], 0.f));
    }

    // --- phase E: v0 (threads 0..511: 32 outputs x 16 threads x 36 k) + skip (wave 8) ---
    if (t < 512) {
        int o = t >> 4, sub = t & 15;
        const ushort* wr = Wv0h + (size_t)o * 576 + sub * 36;
        const float* bp = &baseS[sub * 36];
        float s = 0.f;
#pragma unroll
        for (int j = 0; j < 36; j += 4) {
            ushort4 q = *(const ushort4*)(wr + j);
            s += bp[j + 0] * bf2f(q.x) + bp[j + 1] * bf2f(q.y)
               + bp[j + 2] * bf2f(q.z) + bp[j + 3] * bf2f(q.w);
        }
        s += __shfl_xor(s, 1); s += __shfl_xor(s, 2);
        s += __shfl_xor(s, 4); s += __shfl_xor(s, 8);
        if (sub == 0) v0s[o] = fmaxf(s + b_v0[o], 0.f);
    } else {
        int u = t - 512;   // full wave 8: lanes 0..63
        const float* wp = W_vs + u * 9;
        const float* bp = &baseS[u * 9];
        float s = 0.f;
#pragma unroll
        for (int j = 0; j < 9; ++j) s += bp[j] * wp[j];
        s += __shfl_xor(s, 1); s += __shfl_xor(s, 2); s += __shfl_xor(s, 4);
        s += __shfl_xor(s, 8); s += __shfl_xor(s, 16); s += __shfl_xor(s, 32);
        if (u == 0) skipS = s;
    }
    __syncthreads();

    // --- phase F: v1, v2, combine ---
    if (t < 32) {
        float s = b_v1[t];
        const float* w = W_v1 + (size_t)t * 32;
#pragma unroll
        for (int j = 0; j < 32; ++j) s += v0s[j] * w[j];
        float part = fmaxf(s, 0.f) * W_v2[t];
        part += __shfl_xor(part, 1); part += __shfl_xor(part, 2); part += __shfl_xor(part, 4);
        part += __shfl_xor(part, 8); part += __shfl_xor(part, 16);
        if (t == 0) outv[b] = part + b_v2[0] + skipS + b_vs[0];
    }
}

// ---------------- kernel 4: act GEMM (bf16 MFMA 16x16x32, 128x128 tiles), f32 out ----------------
__global__ __launch_bounds__(256) void gemm_act(const ushort* __restrict__ A,    // hidden [2048,736]
                                                const ushort* __restrict__ Bm,   // Wcat  [4096,736]
                                                const float* __restrict__ biasA, // [4096]
                                                float* __restrict__ outa) {      // [2048,4096] f32
    __shared__ ushort As[128 * 32];
    __shared__ ushort Bs[128 * 32];
    int tid = threadIdx.x;
    int lane = tid & 63, wv = tid >> 6;
    int bm = blockIdx.x, bn = blockIdx.y;
    int wm = wv & 1, wn = wv >> 1;
    f32x4 acc[4][4];
#pragma unroll
    for (int mt = 0; mt < 4; ++mt)
#pragma unroll
        for (int nt = 0; nt < 4; ++nt) { f32x4 z = {0.f, 0.f, 0.f, 0.f}; acc[mt][nt] = z; }

    int r = tid >> 2, c8 = (tid & 3) * 8;
    const ushort* Ag = A  + (size_t)(bm * 128 + r) * KP + c8;
    const ushort* Bg = Bm + (size_t)(bn * 128 + r) * KP + c8;
    ushort* AsW = As + wv * 512;
    ushort* BsW = Bs + wv * 512;

    int kg = (lane >> 4) * 8;
    int rA = wm * 64 + (lane & 15);
    int rB = wn * 64 + (lane & 15);

    for (int kk = 0; kk < KP; kk += 32) {
        llds16(Ag + kk, AsW);
        llds16(Ag + (size_t)64 * KP + kk, AsW + 2048);
        llds16(Bg + kk, BsW);
        llds16(Bg + (size_t)64 * KP + kk, BsW + 2048);
        __syncthreads();
        short8 af[4], bf[4];
#pragma unroll
        for (int mt = 0; mt < 4; ++mt) af[mt] = *(const short8*)&As[(rA + mt * 16) * 32 + kg];
#pragma unroll
        for (int nt = 0; nt < 4; ++nt) bf[nt] = *(const short8*)&Bs[(rB + nt * 16) * 32 + kg];
#pragma unroll
        for (int mt = 0; mt < 4; ++mt)
#pragma unroll
            for (int nt = 0; nt < 4; ++nt)
                acc[mt][nt] = __builtin_amdgcn_mfma_f32_16x16x32_bf16(af[mt], bf[nt], acc[mt][nt], 0, 0, 0);
        __syncthreads();
    }

    int colb = bn * 128 + wn * 64 + (lane & 15);
    int rowb = bm * 128 + wm * 64 + ((lane >> 4) << 2);
#pragma unroll
    for (int nt = 0; nt < 4; ++nt) {
        float bia = biasA[colb + nt * 16];
#pragma unroll
        for (int mt = 0; mt < 4; ++mt) {
#pragma unroll
            for (int q = 0; q < 4; ++q) {
                int rr = rowb + mt * 16 + q;
                outa[(size_t)rr * 4096 + colb + nt * 16] = acc[mt][nt][q] + bia;
            }
        }
    }
}

extern "C" void kernel_launch(void* const* d_in, const int* in_sizes, int n_in,
                              void* d_out, int out_size, void* d_ws, size_t ws_size,
                              hipStream_t stream) {
    const float* pov   = (const float*)d_in[0];
    const float* white = (const float*)d_in[1];
    const float* black = (const float*)d_in[2];
    const float* W_w   = (const float*)d_in[3];
    const float* b_w   = (const float*)d_in[4];
    const float* W_b   = (const float*)d_in[5];
    const float* b_b   = (const float*)d_in[6];
    const float* W_v0  = (const float*)d_in[7];
    const float* b_v0  = (const float*)d_in[8];
    const float* W_v1  = (const float*)d_in[9];
    const float* b_v1  = (const float*)d_in[10];
    const float* W_v2  = (const float*)d_in[11];
    const float* b_v2  = (const float*)d_in[12];
    const float* W_a0  = (const float*)d_in[13];
    const float* b_a0  = (const float*)d_in[14];
    const float* W_a1  = (const float*)d_in[15];
    const float* b_a1  = (const float*)d_in[16];
    const float* W_vs  = (const float*)d_in[17];
    const float* b_vs  = (const float*)d_in[18];
    const float* W_as  = (const float*)d_in[19];
    const float* b_as  = (const float*)d_in[20];

    char* ws = (char*)d_ws;
    // ws layout — non-overlapping, ~56.5 MB of the ~1.3 GB workspace:
    ushort* Wtw   = (ushort*)(ws + 0);          // 40960*288*2 = 23,592,960
    ushort* Wtb   = (ushort*)(ws + 23592960);   //            -> 47,185,920
    ushort* hidden= (ushort*)(ws + 47185920);   // 2048*736*2 = 3,014,656 -> 50,200,576
    ushort* Wcat  = (ushort*)(ws + 50200576);   // 4096*736*2 = 6,029,312 -> 56,229,888
    float*  biasA = (float*)(ws + 56229888);    // 4096*4     = 16,384    -> 56,246,272
    ushort* Wa0h  = (ushort*)(ws + 56246272);   // 144*576*2  = 165,888   -> 56,412,160
    ushort* Wv0h  = (ushort*)(ws + 56412160);   // 32*576*2   = 36,864    -> 56,449,024

    float* outp = (float*)d_out;

    transpose_kernel<<<dim3(D_IN / 64, BASEN / 32, 2), 256, 0, stream>>>(W_w, W_b, Wtw, Wtb);
    prep_kernel<<<4096 + 144 + 32, 256, 0, stream>>>(W_a1, W_as, b_a1, b_as, W_a0, W_v0,
                                                     Wcat, biasA, Wa0h, Wv0h);
    row_kernel<<<NB, 576, 0, stream>>>(white, black, Wtw, Wtb, pov, b_w, b_b,
                                       Wa0h, b_a0, Wv0h, b_v0, W_v1, b_v1, W_v2, b_v2,
                                       W_vs, b_vs, hidden, outp);
    gemm_act<<<dim3(2048 / 128, 4096 / 128), 256, 0, stream>>>(hidden, Wcat, biasA, outp + 2048);
}

// Round 6
// 829.343 us; speedup vs baseline: 1.1186x; 1.0512x over previous
//
#include <hip/hip_runtime.h>

#define D_IN 40960
#define NB 2048
#define BASEN 288
#define CAPL 95        // max indices kept per (row,color); mean ~41, sigma ~6.4
#define KP 736         // 160 (a0 padded) + 576 (base)

typedef __attribute__((ext_vector_type(4))) float f32x4;
typedef __attribute__((ext_vector_type(8))) short short8;

__device__ inline float bf2f(ushort u) {
    unsigned v = ((unsigned)u) << 16; float f; __builtin_memcpy(&f, &v, 4); return f;
}
__device__ inline ushort f2bf(float f) {
    unsigned x; __builtin_memcpy(&x, &f, 4);
    unsigned r = (x + 0x7FFFu + ((x >> 16) & 1u)) >> 16; return (ushort)r;
}

__device__ inline void llds16(const void* g, void* l) {
    __builtin_amdgcn_global_load_lds((const __attribute__((address_space(1))) unsigned*)g,
                                     (__attribute__((address_space(3))) unsigned*)l, 16, 0, 0);
}

// ---------------- kernel 1: transpose W_w/W_b f32 [288,40960] -> Wt bf16 [40960,288] ----------------
__global__ __launch_bounds__(256) void transpose_kernel(const float* __restrict__ Ww,
                                                        const float* __restrict__ Wb,
                                                        ushort* __restrict__ Wtw,
                                                        ushort* __restrict__ Wtb) {
    const float* src = blockIdx.z ? Wb : Ww;
    ushort* dst = blockIdx.z ? Wtb : Wtw;
    __shared__ float tile[32][65];
    int i = threadIdx.x;
    int d0 = blockIdx.x * 64, o0 = blockIdx.y * 32;
    int tr = i >> 4, tc4 = (i & 15) * 4;
#pragma unroll
    for (int rep = 0; rep < 2; ++rep) {
        int row = tr + rep * 16;
        float4 u = *(const float4*)&src[(size_t)(o0 + row) * D_IN + d0 + tc4];
        tile[row][tc4] = u.x; tile[row][tc4 + 1] = u.y; tile[row][tc4 + 2] = u.z; tile[row][tc4 + 3] = u.w;
    }
    __syncthreads();
    int dr = i >> 3, oc4 = (i & 7) * 4;
#pragma unroll
    for (int rep = 0; rep < 2; ++rep) {
        int d = dr + rep * 32;
        ushort4 u;
        u.x = f2bf(tile[oc4][d]); u.y = f2bf(tile[oc4 + 1][d]);
        u.z = f2bf(tile[oc4 + 2][d]); u.w = f2bf(tile[oc4 + 3][d]);
        *(ushort4*)&dst[(size_t)(d0 + d) * BASEN + o0 + oc4] = u;
    }
}

// ---------------- kernel 2: prep — Wcat bf16 [4096,736], biasA, Wa0h bf16, Wv0h bf16 ----------------
__global__ __launch_bounds__(256) void prep_kernel(const float* __restrict__ W_a1,
                                                   const float* __restrict__ W_as,
                                                   const float* __restrict__ b_a1,
                                                   const float* __restrict__ b_as,
                                                   const float* __restrict__ W_a0,
                                                   const float* __restrict__ W_v0,
                                                   ushort* __restrict__ Wcat,
                                                   float* __restrict__ biasA,
                                                   ushort* __restrict__ Wa0h,
                                                   ushort* __restrict__ Wv0h) {
    int m = blockIdx.x, t = threadIdx.x;
    if (m < 4096) {
        ushort* dst = Wcat + (size_t)m * KP;
        if (t < 144) dst[t] = f2bf(W_a1[(size_t)m * 144 + t]);
        if (t >= 144 && t < 160) dst[t] = 0;
        for (int j = t; j < 576; j += 256) dst[160 + j] = f2bf(W_as[(size_t)m * 576 + j]);
        if (t == 200) biasA[m] = b_a1[m] + b_as[m];
    } else if (m < 4096 + 144) {
        int r = m - 4096;
        for (int j = t; j < 576; j += 256) Wa0h[(size_t)r * 576 + j] = f2bf(W_a0[(size_t)r * 576 + j]);
    } else {
        int r = m - (4096 + 144);      // 0..31
        for (int j = t; j < 576; j += 256) Wv0h[(size_t)r * 576 + j] = f2bf(W_v0[(size_t)r * 576 + j]);
    }
}

// ---------------- kernel 3: fused per-row: scan + gather + mix + a0 + value head ----------------
// hidden row layout [736]: [0..143]=a0, [144..159]=0, [160..735]=base
__global__ __launch_bounds__(576) void row_kernel(const float* __restrict__ white,
                                                  const float* __restrict__ black,
                                                  const ushort* __restrict__ Wtw,
                                                  const ushort* __restrict__ Wtb,
                                                  const float* __restrict__ pov,
                                                  const float* __restrict__ b_w,
                                                  const float* __restrict__ b_b,
                                                  const ushort* __restrict__ Wa0h,
                                                  const float* __restrict__ b_a0,
                                                  const ushort* __restrict__ Wv0h,
                                                  const float* __restrict__ b_v0,
                                                  const float* __restrict__ W_v1,
                                                  const float* __restrict__ b_v1,
                                                  const float* __restrict__ W_v2,
                                                  const float* __restrict__ b_v2,
                                                  const float* __restrict__ W_vs,
                                                  const float* __restrict__ b_vs,
                                                  ushort* __restrict__ hidden,
                                                  float* __restrict__ outv) {
    int b = blockIdx.x, t = threadIdx.x;
    __shared__ int cntW, cntB;
    __shared__ int idxW[CAPL], idxB[CAPL];
    __shared__ float accS[576];
    __shared__ float baseS[576];
    __shared__ float v0s[32];
    __shared__ float skipS;
    if (t == 0) cntW = 0;
    if (t == 1) cntB = 0;
    __syncthreads();

    // --- phase A: scan both occupancy rows, batched for MLP ---
    // 8 unconditional 16B loads in flight per thread per batch (index clamped,
    // validity tested after) — breaks the load->waitcnt->branch serialization.
    {
        const uint4* vw = (const uint4*)(white + (size_t)b * D_IN);
        const uint4* vb = (const uint4*)(black + (size_t)b * D_IN);
        const int NV = D_IN / 4;   // 10240 uint4 per color
#pragma unroll
        for (int base = 0; base < NV; base += 576 * 4) {   // 5 batches
            uint4 xw[4], xb[4];
            int id[4];
#pragma unroll
            for (int u = 0; u < 4; ++u) {
                int i = base + u * 576 + t;
                id[u] = i;
                int ic = i < NV ? i : NV - 1;
                xw[u] = vw[ic];
                xb[u] = vb[ic];
            }
#pragma unroll
            for (int u = 0; u < 4; ++u) {
                bool valid = id[u] < NV;
                uint4 x = xw[u];
                if (valid && (x.x | x.y | x.z | x.w)) {
                    int i4 = id[u] * 4;
                    if (x.x) { int p = atomicAdd(&cntW, 1); if (p < CAPL) idxW[p] = i4; }
                    if (x.y) { int p = atomicAdd(&cntW, 1); if (p < CAPL) idxW[p] = i4 + 1; }
                    if (x.z) { int p = atomicAdd(&cntW, 1); if (p < CAPL) idxW[p] = i4 + 2; }
                    if (x.w) { int p = atomicAdd(&cntW, 1); if (p < CAPL) idxW[p] = i4 + 3; }
                }
                uint4 y = xb[u];
                if (valid && (y.x | y.y | y.z | y.w)) {
                    int i4 = id[u] * 4;
                    if (y.x) { int p = atomicAdd(&cntB, 1); if (p < CAPL) idxB[p] = i4; }
                    if (y.y) { int p = atomicAdd(&cntB, 1); if (p < CAPL) idxB[p] = i4 + 1; }
                    if (y.z) { int p = atomicAdd(&cntB, 1); if (p < CAPL) idxB[p] = i4 + 2; }
                    if (y.w) { int p = atomicAdd(&cntB, 1); if (p < CAPL) idxB[p] = i4 + 3; }
                }
            }
        }
    }
    __syncthreads();

    // --- phase B: gather-sum (threads 0..287 white, 288..575 black) ---
    {
        int col = (t < 288) ? t : t - 288;
        const ushort* Wt = (t < 288) ? Wtw : Wtb;
        const int* il = (t < 288) ? idxW : idxB;
        int n = min((t < 288) ? cntW : cntB, CAPL);
        float acc = (t < 288) ? b_w[col] : b_b[col];
#pragma unroll 4
        for (int i = 0; i < n; ++i) acc += bf2f(Wt[(size_t)il[i] * BASEN + col]);
        accS[t] = acc;
    }
    __syncthreads();

    // --- phase C: pov mix + relu -> baseS, write hidden base ---
    float p = pov[b];
    ushort* hrow = hidden + (size_t)b * KP;
    if (t < 288) {
        float aW = accS[t], aB = accS[288 + t];
        float b0 = fmaxf(p * aW + (1.0f - p) * aB, 0.0f);
        float b1 = fmaxf(p * aB + (1.0f - p) * aW, 0.0f);
        baseS[t] = b0; baseS[288 + t] = b1;
        hrow[160 + t] = f2bf(b0);
        hrow[160 + 288 + t] = f2bf(b1);
        if (t < 16) hrow[144 + t] = 0;
    }
    __syncthreads();

    // --- phase D: a0 = relu(W_a0 @ base + b_a0): 144 outputs x 4 threads x 144 k ---
    {
        int o = t >> 2, q4 = t & 3;
        const ushort* wr = Wa0h + (size_t)o * 576 + q4 * 144;
        const float* bp = &baseS[q4 * 144];
        float s = 0.f;
#pragma unroll
        for (int j = 0; j < 144; j += 8) {
            uint4 q = *(const uint4*)(wr + j);
            s += bp[j + 0] * bf2f((ushort)(q.x & 0xFFFF)) + bp[j + 1] * bf2f((ushort)(q.x >> 16))
               + bp[j + 2] * bf2f((ushort)(q.y & 0xFFFF)) + bp[j + 3] * bf2f((ushort)(q.y >> 16))
               + bp[j + 4] * bf2f((ushort)(q.z & 0xFFFF)) + bp[j + 5] * bf2f((ushort)(q.z >> 16))
               + bp[j + 6] * bf2f((ushort)(q.w & 0xFFFF)) + bp[j + 7] * bf2f((ushort)(q.w >> 16));
        }
        s += __shfl_xor(s, 1);
        s += __shfl_xor(s, 2);
        if (q4 == 0) hrow[o] = f2bf(fmaxf(s + b_a0[o], 0.f));
    }

    // --- phase E: v0 (threads 0..511: 32 outputs x 16 threads x 36 k) + skip (wave 8) ---
    if (t < 512) {
        int o = t >> 4, sub = t & 15;
        const ushort* wr = Wv0h + (size_t)o * 576 + sub * 36;
        const float* bp = &baseS[sub * 36];
        float s = 0.f;
#pragma unroll
        for (int j = 0; j < 36; j += 4) {
            ushort4 q = *(const ushort4*)(wr + j);
            s += bp[j + 0] * bf2f(q.x) + bp[j + 1] * bf2f(q.y)
               + bp[j + 2] * bf2f(q.z) + bp[j + 3] * bf2f(q.w);
        }
        s += __shfl_xor(s, 1); s += __shfl_xor(s, 2);
        s += __shfl_xor(s, 4); s += __shfl_xor(s, 8);
        if (sub == 0) v0s[o] = fmaxf(s + b_v0[o], 0.f);
    } else {
        int u = t - 512;   // full wave 8: lanes 0..63
        const float* wp = W_vs + u * 9;
        const float* bp = &baseS[u * 9];
        float s = 0.f;
#pragma unroll
        for (int j = 0; j < 9; ++j) s += bp[j] * wp[j];
        s += __shfl_xor(s, 1); s += __shfl_xor(s, 2); s += __shfl_xor(s, 4);
        s += __shfl_xor(s, 8); s += __shfl_xor(s, 16); s += __shfl_xor(s, 32);
        if (u == 0) skipS = s;
    }
    __syncthreads();

    // --- phase F: v1, v2, combine ---
    if (t < 32) {
        float s = b_v1[t];
        const float* w = W_v1 + (size_t)t * 32;
#pragma unroll
        for (int j = 0; j < 32; ++j) s += v0s[j] * w[j];
        float part = fmaxf(s, 0.f) * W_v2[t];
        part += __shfl_xor(part, 1); part += __shfl_xor(part, 2); part += __shfl_xor(part, 4);
        part += __shfl_xor(part, 8); part += __shfl_xor(part, 16);
        if (t == 0) outv[b] = part + b_v2[0] + skipS + b_vs[0];
    }
}

// ---------------- kernel 4: act GEMM (bf16 MFMA 16x16x32, 128x128 tiles), f32 out ----------------
__global__ __launch_bounds__(256) void gemm_act(const ushort* __restrict__ A,    // hidden [2048,736]
                                                const ushort* __restrict__ Bm,   // Wcat  [4096,736]
                                                const float* __restrict__ biasA, // [4096]
                                                float* __restrict__ outa) {      // [2048,4096] f32
    __shared__ ushort As[128 * 32];
    __shared__ ushort Bs[128 * 32];
    int tid = threadIdx.x;
    int lane = tid & 63, wv = tid >> 6;
    int bm = blockIdx.x, bn = blockIdx.y;
    int wm = wv & 1, wn = wv >> 1;
    f32x4 acc[4][4];
#pragma unroll
    for (int mt = 0; mt < 4; ++mt)
#pragma unroll
        for (int nt = 0; nt < 4; ++nt) { f32x4 z = {0.f, 0.f, 0.f, 0.f}; acc[mt][nt] = z; }

    int r = tid >> 2, c8 = (tid & 3) * 8;
    const ushort* Ag = A  + (size_t)(bm * 128 + r) * KP + c8;
    const ushort* Bg = Bm + (size_t)(bn * 128 + r) * KP + c8;
    ushort* AsW = As + wv * 512;
    ushort* BsW = Bs + wv * 512;

    int kg = (lane >> 4) * 8;
    int rA = wm * 64 + (lane & 15);
    int rB = wn * 64 + (lane & 15);

    for (int kk = 0; kk < KP; kk += 32) {
        llds16(Ag + kk, AsW);
        llds16(Ag + (size_t)64 * KP + kk, AsW + 2048);
        llds16(Bg + kk, BsW);
        llds16(Bg + (size_t)64 * KP + kk, BsW + 2048);
        __syncthreads();
        short8 af[4], bf[4];
#pragma unroll
        for (int mt = 0; mt < 4; ++mt) af[mt] = *(const short8*)&As[(rA + mt * 16) * 32 + kg];
#pragma unroll
        for (int nt = 0; nt < 4; ++nt) bf[nt] = *(const short8*)&Bs[(rB + nt * 16) * 32 + kg];
#pragma unroll
        for (int mt = 0; mt < 4; ++mt)
#pragma unroll
            for (int nt = 0; nt < 4; ++nt)
                acc[mt][nt] = __builtin_amdgcn_mfma_f32_16x16x32_bf16(af[mt], bf[nt], acc[mt][nt], 0, 0, 0);
        __syncthreads();
    }

    int colb = bn * 128 + wn * 64 + (lane & 15);
    int rowb = bm * 128 + wm * 64 + ((lane >> 4) << 2);
#pragma unroll
    for (int nt = 0; nt < 4; ++nt) {
        float bia = biasA[colb + nt * 16];
#pragma unroll
        for (int mt = 0; mt < 4; ++mt) {
#pragma unroll
            for (int q = 0; q < 4; ++q) {
                int rr = rowb + mt * 16 + q;
                outa[(size_t)rr * 4096 + colb + nt * 16] = acc[mt][nt][q] + bia;
            }
        }
    }
}

extern "C" void kernel_launch(void* const* d_in, const int* in_sizes, int n_in,
                              void* d_out, int out_size, void* d_ws, size_t ws_size,
                              hipStream_t stream) {
    const float* pov   = (const float*)d_in[0];
    const float* white = (const float*)d_in[1];
    const float* black = (const float*)d_in[2];
    const float* W_w   = (const float*)d_in[3];
    const float* b_w   = (const float*)d_in[4];
    const float* W_b   = (const float*)d_in[5];
    const float* b_b   = (const float*)d_in[6];
    const float* W_v0  = (const float*)d_in[7];
    const float* b_v0  = (const float*)d_in[8];
    const float* W_v1  = (const float*)d_in[9];
    const float* b_v1  = (const float*)d_in[10];
    const float* W_v2  = (const float*)d_in[11];
    const float* b_v2  = (const float*)d_in[12];
    const float* W_a0  = (const float*)d_in[13];
    const float* b_a0  = (const float*)d_in[14];
    const float* W_a1  = (const float*)d_in[15];
    const float* b_a1  = (const float*)d_in[16];
    const float* W_vs  = (const float*)d_in[17];
    const float* b_vs  = (const float*)d_in[18];
    const float* W_as  = (const float*)d_in[19];
    const float* b_as  = (const float*)d_in[20];

    char* ws = (char*)d_ws;
    // ws layout — non-overlapping, ~56.5 MB of the ~1.3 GB workspace:
    ushort* Wtw   = (ushort*)(ws + 0);          // 40960*288*2 = 23,592,960
    ushort* Wtb   = (ushort*)(ws + 23592960);   //            -> 47,185,920
    ushort* hidden= (ushort*)(ws + 47185920);   // 2048*736*2 = 3,014,656 -> 50,200,576
    ushort* Wcat  = (ushort*)(ws + 50200576);   // 4096*736*2 = 6,029,312 -> 56,229,888
    float*  biasA = (float*)(ws + 56229888);    // 4096*4     = 16,384    -> 56,246,272
    ushort* Wa0h  = (ushort*)(ws + 56246272);   // 144*576*2  = 165,888   -> 56,412,160
    ushort* Wv0h  = (ushort*)(ws + 56412160);   // 32*576*2   = 36,864    -> 56,449,024

    float* outp = (float*)d_out;

    transpose_kernel<<<dim3(D_IN / 64, BASEN / 32, 2), 256, 0, stream>>>(W_w, W_b, Wtw, Wtb);
    prep_kernel<<<4096 + 144 + 32, 256, 0, stream>>>(W_a1, W_as, b_a1, b_as, W_a0, W_v0,
                                                     Wcat, biasA, Wa0h, Wv0h);
    row_kernel<<<NB, 576, 0, stream>>>(white, black, Wtw, Wtb, pov, b_w, b_b,
                                       Wa0h, b_a0, Wv0h, b_v0, W_v1, b_v1, W_v2, b_v2,
                                       W_vs, b_vs, hidden, outp);
    gemm_act<<<dim3(2048 / 128, 4096 / 128), 256, 0, stream>>>(hidden, Wcat, biasA, outp + 2048);
}